// Round 5
// baseline (1595.449 us; speedup 1.0000x reference)
//
#include <hip/hip_runtime.h>
#include <hip/hip_bf16.h>

#define DFEAT 64
#define BNODES 128            // nodes per bucket
#define NSUB 8                // sub-buckets (XCD-locality heuristic via blockIdx&7)
#define CAP8 384              // capacity per (bucket,sub): mean 256, sd 16 -> +8 sigma

// ---------------- bucket build ----------------

__global__ __launch_bounds__(256) void zero_cur_k(int* __restrict__ bcur, int n) {
    int i = blockIdx.x * 256 + threadIdx.x;
    if (i < n) bcur[i] = 0;
}

// append packed (dstLocal<<25 | src) into sub-bucket (dst>>7, blockIdx&7)
__global__ __launch_bounds__(256) void bucketize_k(const int* __restrict__ src,
                                                   const int* __restrict__ dst,
                                                   int* __restrict__ bcur,
                                                   unsigned* __restrict__ barr, int E) {
    int e = blockIdx.x * 256 + threadIdx.x;
    if (e >= E) return;
    int d = dst[e];
    int b = d >> 7;
    unsigned w = ((unsigned)(d & 127) << 25) | (unsigned)src[e];
    int sub = blockIdx.x & (NSUB - 1);
    int pos = atomicAdd(&bcur[b * NSUB + sub], 1);
    if (pos < CAP8) barr[(size_t)(b * NSUB + sub) * CAP8 + pos] = w;
}

// dinv[node] = rsqrt(indeg+1), computed from buckets (one block per bucket)
__global__ __launch_bounds__(256) void dinv_k(const int* __restrict__ bcur,
                                              const unsigned* __restrict__ barr,
                                              float* __restrict__ dinv, int N) {
    __shared__ int cnt[BNODES];
    int b = blockIdx.x;
    if (threadIdx.x < BNODES) cnt[threadIdx.x] = 0;
    __syncthreads();
    for (int s = 0; s < NSUB; ++s) {
        int n = min(bcur[b * NSUB + s], CAP8);
        const unsigned* p = barr + (size_t)(b * NSUB + s) * CAP8;
        for (int i = threadIdx.x; i < n; i += 256) atomicAdd(&cnt[p[i] >> 25], 1);
    }
    __syncthreads();
    if (threadIdx.x < BNODES) {
        int node = b * BNODES + threadIdx.x;
        if (node < N) dinv[node] = rsqrtf((float)cnt[threadIdx.x] + 1.0f);
    }
}

// ---------------- dense GEMM: A[n,64] = bf16( scale[n] * (X[n,64] @ W[64,64]) ) ----------------

__global__ __launch_bounds__(256) void gemm64_k(const float* __restrict__ X,
                                                const float* __restrict__ W,
                                                const float* __restrict__ scale,
                                                __hip_bfloat16* __restrict__ A, int nrows) {
    __shared__ float Ws[64 * 64];
    __shared__ float Xs[4 * 64];
    for (int i = threadIdx.x; i < 64 * 64; i += 256) Ws[i] = W[i];
    int lane = threadIdx.x & 63;
    int wv = threadIdx.x >> 6;

    for (int base = blockIdx.x * 4; base < nrows; base += gridDim.x * 4) {
        __syncthreads();
        {
            int rr = base + (threadIdx.x >> 6);
            Xs[threadIdx.x] = (rr < nrows) ? X[rr * 64 + (threadIdx.x & 63)] : 0.0f;
        }
        __syncthreads();
        int r = base + wv;
        if (r < nrows) {
            float acc = 0.0f;
#pragma unroll
            for (int k = 0; k < 64; ++k)
                acc += Xs[wv * 64 + k] * Ws[k * 64 + lane];
            A[r * 64 + lane] = __float2bfloat16(acc * scale[r]);
        }
    }
}

// ---------------- bucketed aggregation (one block per 128-node bucket) ----------------
// acc_lds[dl] += A[src] over all bucket edges, then fused epilogue.

#define AGG_BODY(EPILOGUE)                                                               \
    __shared__ float acc[BNODES * DFEAT]; /* 32 KB */                                    \
    int b = blockIdx.x;                                                                  \
    int lane = threadIdx.x & 63;                                                         \
    int wv = threadIdx.x >> 6;                                                           \
    for (int i = threadIdx.x; i < BNODES * DFEAT; i += 256) acc[i] = 0.0f;               \
    __syncthreads();                                                                     \
    for (int s = wv; s < NSUB; s += 4) {                                                 \
        int cnt = min(bcur[b * NSUB + s], CAP8);                                         \
        const unsigned* p = barr + (size_t)(b * NSUB + s) * CAP8;                        \
        for (int base = 0; base < cnt; base += 64) {                                     \
            unsigned w = (base + lane < cnt) ? p[base + lane] : 0u;                      \
            int n = min(64, cnt - base);                                                 \
            int i = 0;                                                                   \
            for (; i + 4 <= n; i += 4) {                                                 \
                unsigned w0 = __shfl(w, i), w1 = __shfl(w, i + 1);                       \
                unsigned w2 = __shfl(w, i + 2), w3 = __shfl(w, i + 3);                   \
                float v0 = __bfloat162float(A[(w0 & 0x1FFFFFFu) * 64 + lane]);           \
                float v1 = __bfloat162float(A[(w1 & 0x1FFFFFFu) * 64 + lane]);           \
                float v2 = __bfloat162float(A[(w2 & 0x1FFFFFFu) * 64 + lane]);           \
                float v3 = __bfloat162float(A[(w3 & 0x1FFFFFFu) * 64 + lane]);           \
                atomicAdd(&acc[(w0 >> 25) * DFEAT + lane], v0);                          \
                atomicAdd(&acc[(w1 >> 25) * DFEAT + lane], v1);                          \
                atomicAdd(&acc[(w2 >> 25) * DFEAT + lane], v2);                          \
                atomicAdd(&acc[(w3 >> 25) * DFEAT + lane], v3);                          \
            }                                                                            \
            for (; i < n; ++i) {                                                         \
                unsigned wi = __shfl(w, i);                                              \
                float vi = __bfloat162float(A[(wi & 0x1FFFFFFu) * 64 + lane]);           \
                atomicAdd(&acc[(wi >> 25) * DFEAT + lane], vi);                          \
            }                                                                            \
        }                                                                                \
    }                                                                                    \
    __syncthreads();                                                                     \
    for (int ln = wv; ln < BNODES; ln += 4) {                                            \
        int node = b * BNODES + ln;                                                      \
        if (node < N) {                                                                  \
            size_t idx = (size_t)node * 64 + lane;                                       \
            float v = acc[ln * DFEAT + lane] + __bfloat162float(A[idx]);                 \
            EPILOGUE;                                                                    \
        }                                                                                \
    }

__global__ __launch_bounds__(256) void agg_relu_k(const int* __restrict__ bcur,
                                                  const unsigned* __restrict__ barr,
                                                  const __hip_bfloat16* __restrict__ A,
                                                  const float* __restrict__ dinv,
                                                  const float* __restrict__ bias,
                                                  float* __restrict__ out, int N) {
    AGG_BODY(out[idx] = fmaxf(fmaf(dinv[node], v, bias[lane]), 0.0f))
}

__global__ __launch_bounds__(256) void agg_res_k(const int* __restrict__ bcur,
                                                 const unsigned* __restrict__ barr,
                                                 const __hip_bfloat16* __restrict__ A,
                                                 const float* __restrict__ dinv,
                                                 const float* __restrict__ bias,
                                                 const float* __restrict__ xres,
                                                 float* __restrict__ out, int N) {
    AGG_BODY(out[idx] = fmaf(dinv[node], v, bias[lane] + xres[idx]))
}

// ---------------- launch ----------------

extern "C" void kernel_launch(void* const* d_in, const int* in_sizes, int n_in,
                              void* d_out, int out_size, void* d_ws, size_t ws_size,
                              hipStream_t stream) {
    const float* x = (const float*)d_in[0];
    const int* ei = (const int*)d_in[1];  // int32 per harness
    const float* W1 = (const float*)d_in[2];
    const float* b1 = (const float*)d_in[3];
    const float* W2 = (const float*)d_in[4];
    const float* b2 = (const float*)d_in[5];
    float* out = (float*)d_out;

    const int N = in_sizes[0] / DFEAT;  // 100000
    const int E = in_sizes[1] / 2;      // 1600000
    const int NB = (N + BNODES - 1) / BNODES;  // 782

    const int* src = ei;
    const int* dst = ei + E;

    // workspace (~23 MB)
    char* w = (char*)d_ws;
    size_t o = 0;
    __hip_bfloat16* A = (__hip_bfloat16*)(w + o); o += (size_t)N * DFEAT * 2;  // 12.8 MB
    float* dinv = (float*)(w + o);                o += (size_t)N * 4;          // 0.4 MB
    int* bcur = (int*)(w + o);                    o += (size_t)NB * NSUB * 4;  // 25 KB
    unsigned* barr = (unsigned*)(w + o);          // NB*NSUB*CAP8*4 = 9.6 MB

    const int gE = (E + 255) / 256;
    const int gC = (NB * NSUB + 255) / 256;

    // bucket build (shared by both layers)
    zero_cur_k<<<gC, 256, 0, stream>>>(bcur, NB * NSUB);
    bucketize_k<<<gE, 256, 0, stream>>>(src, dst, bcur, barr, E);
    dinv_k<<<NB, 256, 0, stream>>>(bcur, barr, dinv, N);

    // ---- layer 1 ----
    gemm64_k<<<1024, 256, 0, stream>>>(x, W1, dinv, A, N);  // A = bf16(dinv*(x@W1))
    agg_relu_k<<<NB, 256, 0, stream>>>(bcur, barr, A, dinv, b1, out, N);

    // ---- layer 2 ---- (x1 lives in d_out, consumed by gemm before agg overwrites)
    gemm64_k<<<1024, 256, 0, stream>>>(out, W2, dinv, A, N);  // A = bf16(dinv*(x1@W2))
    agg_res_k<<<NB, 256, 0, stream>>>(bcur, barr, A, dinv, b2, x, out, N);
}

// Round 6
// 276.245 us; speedup vs baseline: 5.7755x; 5.7755x over previous
//
#include <hip/hip_runtime.h>
#include <hip/hip_bf16.h>

#define DFEAT 64
#define BNODES 128            // nodes per bucket
#define NSUB 8                // sub-buckets per bucket (write-locality)
#define CAP8 384              // capacity per (bucket,sub): mean 256, sd 16 -> +8 sigma
#define BCAP (NSUB * CAP8)    // 3072 edge slots per bucket

// ---------------- bucket build ----------------

__global__ __launch_bounds__(256) void zero_cur_k(int* __restrict__ bcur, int n) {
    int i = blockIdx.x * 256 + threadIdx.x;
    if (i < n) bcur[i] = 0;
}

// append packed (dstLocal<<25 | src) into sub-bucket (dst>>7, blockIdx&7)
__global__ __launch_bounds__(256) void bucketize_k(const int* __restrict__ src,
                                                   const int* __restrict__ dst,
                                                   int* __restrict__ bcur,
                                                   unsigned* __restrict__ barr, int E) {
    int e = blockIdx.x * 256 + threadIdx.x;
    if (e >= E) return;
    int d = dst[e];
    int b = d >> 7;
    unsigned w = ((unsigned)(d & 127) << 25) | (unsigned)src[e];
    int sub = blockIdx.x & (NSUB - 1);
    int pos = atomicAdd(&bcur[b * NSUB + sub], 1);
    if (pos < CAP8) barr[(size_t)(b * NSUB + sub) * CAP8 + pos] = w;
}

// one block per bucket: count per-node, LDS scan, scatter into sorted order,
// coalesced write-out of edge list + per-node meta (off<<16|cnt) + dinv.
__global__ __launch_bounds__(256) void localsort_k(const int* __restrict__ bcur,
                                                   const unsigned* __restrict__ barr,
                                                   int* __restrict__ csr,
                                                   int* __restrict__ meta,
                                                   float* __restrict__ dinv, int N) {
    __shared__ int cnt[BNODES];
    __shared__ int off[BNODES];
    __shared__ int cur[BNODES];
    __shared__ int sorted[BCAP];
    int b = blockIdx.x;
    if (threadIdx.x < BNODES) cnt[threadIdx.x] = 0;
    __syncthreads();
    // pass 1: count
    for (int s = 0; s < NSUB; ++s) {
        int n = min(bcur[b * NSUB + s], CAP8);
        const unsigned* p = barr + (size_t)(b * NSUB + s) * CAP8;
        for (int i = threadIdx.x; i < n; i += 256) atomicAdd(&cnt[p[i] >> 25], 1);
    }
    __syncthreads();
    // inclusive scan over 128 counts (Hillis-Steele)
    if (threadIdx.x < BNODES) off[threadIdx.x] = cnt[threadIdx.x];
    __syncthreads();
    for (int d = 1; d < BNODES; d <<= 1) {
        int v = 0;
        if (threadIdx.x < BNODES && threadIdx.x >= d) v = off[threadIdx.x - d];
        __syncthreads();
        if (threadIdx.x < BNODES) off[threadIdx.x] += v;
        __syncthreads();
    }
    if (threadIdx.x < BNODES) {
        int ex = off[threadIdx.x] - cnt[threadIdx.x];
        cur[threadIdx.x] = ex;
        int node = b * BNODES + threadIdx.x;
        if (node < N) {
            meta[node] = (ex << 16) | cnt[threadIdx.x];
            dinv[node] = rsqrtf((float)cnt[threadIdx.x] + 1.0f);  // +1 self loop
        }
    }
    __syncthreads();
    // pass 2: scatter into LDS in sorted order
    for (int s = 0; s < NSUB; ++s) {
        int n = min(bcur[b * NSUB + s], CAP8);
        const unsigned* p = barr + (size_t)(b * NSUB + s) * CAP8;
        for (int i = threadIdx.x; i < n; i += 256) {
            unsigned w = p[i];
            int pos = atomicAdd(&cur[w >> 25], 1);
            sorted[pos] = (int)(w & 0x1FFFFFFu);
        }
    }
    __syncthreads();
    int tot = off[BNODES - 1];
    for (int i = threadIdx.x; i < tot; i += 256) csr[(size_t)b * BCAP + i] = sorted[i];
}

// ---------------- dense GEMM: A[n,64] = bf16( scale[n] * (X[n,64] @ W[64,64]) ) ----------------

__global__ __launch_bounds__(256) void gemm64_k(const float* __restrict__ X,
                                                const float* __restrict__ W,
                                                const float* __restrict__ scale,
                                                __hip_bfloat16* __restrict__ A, int nrows) {
    __shared__ float Ws[64 * 64];
    __shared__ float Xs[4 * 64];
    for (int i = threadIdx.x; i < 64 * 64; i += 256) Ws[i] = W[i];
    int lane = threadIdx.x & 63;
    int wv = threadIdx.x >> 6;

    for (int base = blockIdx.x * 4; base < nrows; base += gridDim.x * 4) {
        __syncthreads();
        {
            int rr = base + (threadIdx.x >> 6);
            Xs[threadIdx.x] = (rr < nrows) ? X[rr * 64 + (threadIdx.x & 63)] : 0.0f;
        }
        __syncthreads();
        int r = base + wv;
        if (r < nrows) {
            float acc = 0.0f;
#pragma unroll
            for (int k = 0; k < 64; ++k)
                acc += Xs[wv * 64 + k] * Ws[k * 64 + lane];
            A[r * 64 + lane] = __float2bfloat16(acc * scale[r]);
        }
    }
}

// ---------------- gather aggregation: 2 nodes per wave, 32 lanes per bf16 row ----------------
// Each lane owns feature pair (2*lane, 2*lane+1) as one dword of packed bf16.

__device__ __forceinline__ float bflo(unsigned u) { return __uint_as_float(u << 16); }
__device__ __forceinline__ float bfhi(unsigned u) { return __uint_as_float(u & 0xFFFF0000u); }

#define GATHER_BODY(EPILOGUE)                                                     \
    int lane = threadIdx.x & 31;                                                  \
    int node = blockIdx.x * 8 + (threadIdx.x >> 5);                               \
    if (node >= N) return;                                                        \
    int m = meta[node];                                                           \
    int cnt = m & 0xFFFF;                                                         \
    const int* lst = csr + (size_t)(node >> 7) * BCAP + (m >> 16);                \
    unsigned su = Au[(size_t)node * 32 + lane];                                   \
    float ax = bflo(su), ay = bfhi(su); /* self loop */                           \
    int i = 0;                                                                    \
    for (; i + 4 <= cnt; i += 4) {                                                \
        int s0 = lst[i], s1 = lst[i + 1], s2 = lst[i + 2], s3 = lst[i + 3];       \
        unsigned u0 = Au[(size_t)s0 * 32 + lane];                                 \
        unsigned u1 = Au[(size_t)s1 * 32 + lane];                                 \
        unsigned u2 = Au[(size_t)s2 * 32 + lane];                                 \
        unsigned u3 = Au[(size_t)s3 * 32 + lane];                                 \
        ax += (bflo(u0) + bflo(u1)) + (bflo(u2) + bflo(u3));                      \
        ay += (bfhi(u0) + bfhi(u1)) + (bfhi(u2) + bfhi(u3));                      \
    }                                                                             \
    for (; i < cnt; ++i) {                                                        \
        unsigned u = Au[(size_t)lst[i] * 32 + lane];                              \
        ax += bflo(u);                                                            \
        ay += bfhi(u);                                                            \
    }                                                                             \
    float d = dinv[node];                                                         \
    float bx = bias[2 * lane], by = bias[2 * lane + 1];                           \
    EPILOGUE;

__global__ __launch_bounds__(256) void gat_relu_k(const int* __restrict__ meta,
                                                  const int* __restrict__ csr,
                                                  const unsigned* __restrict__ Au,
                                                  const float* __restrict__ dinv,
                                                  const float* __restrict__ bias,
                                                  float* __restrict__ out, int N) {
    GATHER_BODY({
        float2 r;
        r.x = fmaxf(fmaf(d, ax, bx), 0.0f);
        r.y = fmaxf(fmaf(d, ay, by), 0.0f);
        ((float2*)out)[(size_t)node * 32 + lane] = r;
    })
}

__global__ __launch_bounds__(256) void gat_res_k(const int* __restrict__ meta,
                                                 const int* __restrict__ csr,
                                                 const unsigned* __restrict__ Au,
                                                 const float* __restrict__ dinv,
                                                 const float* __restrict__ bias,
                                                 const float* __restrict__ xres,
                                                 float* __restrict__ out, int N) {
    GATHER_BODY({
        float2 xr = ((const float2*)xres)[(size_t)node * 32 + lane];
        float2 r;
        r.x = fmaf(d, ax, bx + xr.x);
        r.y = fmaf(d, ay, by + xr.y);
        ((float2*)out)[(size_t)node * 32 + lane] = r;
    })
}

// ---------------- launch ----------------

extern "C" void kernel_launch(void* const* d_in, const int* in_sizes, int n_in,
                              void* d_out, int out_size, void* d_ws, size_t ws_size,
                              hipStream_t stream) {
    const float* x = (const float*)d_in[0];
    const int* ei = (const int*)d_in[1];  // int32 per harness
    const float* W1 = (const float*)d_in[2];
    const float* b1 = (const float*)d_in[3];
    const float* W2 = (const float*)d_in[4];
    const float* b2 = (const float*)d_in[5];
    float* out = (float*)d_out;

    const int N = in_sizes[0] / DFEAT;          // 100000
    const int E = in_sizes[1] / 2;              // 1600000
    const int NB = (N + BNODES - 1) / BNODES;   // 782

    const int* src = ei;
    const int* dst = ei + E;

    // workspace (~33 MB), 256B-aligned chunks
    char* w = (char*)d_ws;
    size_t o = 0;
    __hip_bfloat16* A = (__hip_bfloat16*)(w + o); o += (size_t)N * DFEAT * 2;        // 12.8 MB
    float* dinv = (float*)(w + o);                o += ((size_t)N * 4 + 255) & ~255; // 0.4 MB
    int* meta = (int*)(w + o);                    o += ((size_t)N * 4 + 255) & ~255; // 0.4 MB
    int* bcur = (int*)(w + o);                    o += ((size_t)NB * NSUB * 4 + 255) & ~255;
    unsigned* barr = (unsigned*)(w + o);          o += (size_t)NB * BCAP * 4;        // 9.6 MB
    int* csr = (int*)(w + o);                     // 9.6 MB

    const int gE = (E + 255) / 256;
    const int gC = (NB * NSUB + 255) / 256;
    const int gG = (N + 7) / 8;

    // ---- build (shared by both layers) ----
    zero_cur_k<<<gC, 256, 0, stream>>>(bcur, NB * NSUB);
    bucketize_k<<<gE, 256, 0, stream>>>(src, dst, bcur, barr, E);
    localsort_k<<<NB, 256, 0, stream>>>(bcur, barr, csr, meta, dinv, N);

    // ---- layer 1 ----
    gemm64_k<<<1024, 256, 0, stream>>>(x, W1, dinv, A, N);  // A = bf16(dinv*(x@W1))
    gat_relu_k<<<gG, 256, 0, stream>>>(meta, csr, (const unsigned*)A, dinv, b1, out, N);

    // ---- layer 2 ---- (x1 lives in d_out, consumed by gemm before overwrite)
    gemm64_k<<<1024, 256, 0, stream>>>(out, W2, dinv, A, N);  // A = bf16(dinv*(x1@W2))
    gat_res_k<<<gG, 256, 0, stream>>>(meta, csr, (const unsigned*)A, dinv, b2, x, out, N);
}

// Round 7
// 217.435 us; speedup vs baseline: 7.3376x; 1.2705x over previous
//
#include <hip/hip_runtime.h>
#include <hip/hip_bf16.h>

#define DFEAT 64
#define BNODES 128            // nodes per bucket
#define BCAP 3072             // edge capacity per bucket: mean 2046, sd ~45 -> +22 sigma
#define EPB 8192              // edges per bucketize block (32/thread)

// ---------------- bucket build ----------------

__global__ __launch_bounds__(256) void zero_cur_k(int* __restrict__ bcur, int n) {
    int i = blockIdx.x * 256 + threadIdx.x;
    if (i < n) bcur[i] = 0;
}

// LDS-staged bucketize: histogram per block, 1 global atomic per non-empty bin,
// then scatter packed (dstLocal<<25|src) words into reserved contiguous runs.
__global__ __launch_bounds__(256) void bucketize_k(const int* __restrict__ src,
                                                   const int* __restrict__ dst,
                                                   int* __restrict__ bcur,
                                                   unsigned* __restrict__ barr,
                                                   int E, int NB) {
    __shared__ unsigned pkbuf[EPB];        // 32 KB packed words
    __shared__ unsigned short bbuf[EPB];   // 16 KB bucket ids
    __shared__ int hist[784];              // counts, then reused as local cursors
    __shared__ int base[784];              // reserved global base per bin

    int tid = threadIdx.x;
    int e0 = blockIdx.x * EPB;
    int n = min(EPB, E - e0);

    for (int t = tid; t < NB; t += 256) hist[t] = 0;
    __syncthreads();

    // pass 1: load, pack, histogram
    for (int k = 0; k < EPB / 256; ++k) {
        int i = k * 256 + tid;
        if (i < n) {
            int d = dst[e0 + i];
            int b = d >> 7;
            pkbuf[i] = ((unsigned)(d & 127) << 25) | (unsigned)src[e0 + i];
            bbuf[i] = (unsigned short)b;
            atomicAdd(&hist[b], 1);
        }
    }
    __syncthreads();

    // reserve global runs: one atomic per non-empty bin; reset hist -> cursor
    for (int t = tid; t < NB; t += 256) {
        int c = hist[t];
        if (c > 0) base[t] = atomicAdd(&bcur[t], c);
        hist[t] = 0;
    }
    __syncthreads();

    // pass 2: scatter from LDS into reserved runs
    for (int k = 0; k < EPB / 256; ++k) {
        int i = k * 256 + tid;
        if (i < n) {
            int b = bbuf[i];
            int loc = atomicAdd(&hist[b], 1);
            int pos = base[b] + loc;
            if (pos < BCAP) barr[(size_t)b * BCAP + pos] = pkbuf[i];
        }
    }
}

// one block per bucket: count per-node, LDS scan, scatter into sorted order,
// coalesced write-out of edge list + per-node meta (off<<16|cnt) + dinv.
__global__ __launch_bounds__(256) void localsort_k(const int* __restrict__ bcur,
                                                   const unsigned* __restrict__ barr,
                                                   int* __restrict__ csr,
                                                   int* __restrict__ meta,
                                                   float* __restrict__ dinv, int N) {
    __shared__ int cnt[BNODES];
    __shared__ int off[BNODES];
    __shared__ int cur[BNODES];
    __shared__ int sorted[BCAP];
    int b = blockIdx.x;
    int nb = min(bcur[b], BCAP);
    const unsigned* p = barr + (size_t)b * BCAP;
    if (threadIdx.x < BNODES) cnt[threadIdx.x] = 0;
    __syncthreads();
    // pass 1: count
    for (int i = threadIdx.x; i < nb; i += 256) atomicAdd(&cnt[p[i] >> 25], 1);
    __syncthreads();
    // inclusive scan over 128 counts (Hillis-Steele)
    if (threadIdx.x < BNODES) off[threadIdx.x] = cnt[threadIdx.x];
    __syncthreads();
    for (int d = 1; d < BNODES; d <<= 1) {
        int v = 0;
        if (threadIdx.x < BNODES && threadIdx.x >= d) v = off[threadIdx.x - d];
        __syncthreads();
        if (threadIdx.x < BNODES) off[threadIdx.x] += v;
        __syncthreads();
    }
    if (threadIdx.x < BNODES) {
        int ex = off[threadIdx.x] - cnt[threadIdx.x];
        cur[threadIdx.x] = ex;
        int node = b * BNODES + threadIdx.x;
        if (node < N) {
            meta[node] = (ex << 16) | cnt[threadIdx.x];
            dinv[node] = rsqrtf((float)cnt[threadIdx.x] + 1.0f);  // +1 self loop
        }
    }
    __syncthreads();
    // pass 2: scatter into LDS in sorted order
    for (int i = threadIdx.x; i < nb; i += 256) {
        unsigned w = p[i];
        int pos = atomicAdd(&cur[w >> 25], 1);
        sorted[pos] = (int)(w & 0x1FFFFFFu);
    }
    __syncthreads();
    int tot = off[BNODES - 1];
    for (int i = threadIdx.x; i < tot; i += 256) csr[(size_t)b * BCAP + i] = sorted[i];
}

// ---------------- dense GEMM: A[n,64] = bf16( scale[n] * (X[n,64] @ W[64,64]) ) ----------------

__global__ __launch_bounds__(256) void gemm64_k(const float* __restrict__ X,
                                                const float* __restrict__ W,
                                                const float* __restrict__ scale,
                                                __hip_bfloat16* __restrict__ A, int nrows) {
    __shared__ float Ws[64 * 64];
    __shared__ float Xs[4 * 64];
    for (int i = threadIdx.x; i < 64 * 64; i += 256) Ws[i] = W[i];
    int lane = threadIdx.x & 63;
    int wv = threadIdx.x >> 6;

    for (int base = blockIdx.x * 4; base < nrows; base += gridDim.x * 4) {
        __syncthreads();
        {
            int rr = base + (threadIdx.x >> 6);
            Xs[threadIdx.x] = (rr < nrows) ? X[rr * 64 + (threadIdx.x & 63)] : 0.0f;
        }
        __syncthreads();
        int r = base + wv;
        if (r < nrows) {
            float acc = 0.0f;
#pragma unroll
            for (int k = 0; k < 64; ++k)
                acc += Xs[wv * 64 + k] * Ws[k * 64 + lane];
            A[r * 64 + lane] = __float2bfloat16(acc * scale[r]);
        }
    }
}

// ---------------- gather aggregation: 2 nodes per wave, 32 lanes per bf16 row ----------------

__device__ __forceinline__ float bflo(unsigned u) { return __uint_as_float(u << 16); }
__device__ __forceinline__ float bfhi(unsigned u) { return __uint_as_float(u & 0xFFFF0000u); }

#define GATHER_BODY(EPILOGUE)                                                     \
    int lane = threadIdx.x & 31;                                                  \
    int node = blockIdx.x * 8 + (threadIdx.x >> 5);                               \
    if (node >= N) return;                                                        \
    int m = meta[node];                                                           \
    int cnt = m & 0xFFFF;                                                         \
    const int* lst = csr + (size_t)(node >> 7) * BCAP + (m >> 16);                \
    unsigned su = Au[(size_t)node * 32 + lane];                                   \
    float ax = bflo(su), ay = bfhi(su); /* self loop */                           \
    int i = 0;                                                                    \
    for (; i + 4 <= cnt; i += 4) {                                                \
        int s0 = lst[i], s1 = lst[i + 1], s2 = lst[i + 2], s3 = lst[i + 3];       \
        unsigned u0 = Au[(size_t)s0 * 32 + lane];                                 \
        unsigned u1 = Au[(size_t)s1 * 32 + lane];                                 \
        unsigned u2 = Au[(size_t)s2 * 32 + lane];                                 \
        unsigned u3 = Au[(size_t)s3 * 32 + lane];                                 \
        ax += (bflo(u0) + bflo(u1)) + (bflo(u2) + bflo(u3));                      \
        ay += (bfhi(u0) + bfhi(u1)) + (bfhi(u2) + bfhi(u3));                      \
    }                                                                             \
    for (; i < cnt; ++i) {                                                        \
        unsigned u = Au[(size_t)lst[i] * 32 + lane];                              \
        ax += bflo(u);                                                            \
        ay += bfhi(u);                                                            \
    }                                                                             \
    float d = dinv[node];                                                         \
    float bx = bias[2 * lane], by = bias[2 * lane + 1];                           \
    EPILOGUE;

__global__ __launch_bounds__(256) void gat_relu_k(const int* __restrict__ meta,
                                                  const int* __restrict__ csr,
                                                  const unsigned* __restrict__ Au,
                                                  const float* __restrict__ dinv,
                                                  const float* __restrict__ bias,
                                                  float* __restrict__ out, int N) {
    GATHER_BODY({
        float2 r;
        r.x = fmaxf(fmaf(d, ax, bx), 0.0f);
        r.y = fmaxf(fmaf(d, ay, by), 0.0f);
        ((float2*)out)[(size_t)node * 32 + lane] = r;
    })
}

__global__ __launch_bounds__(256) void gat_res_k(const int* __restrict__ meta,
                                                 const int* __restrict__ csr,
                                                 const unsigned* __restrict__ Au,
                                                 const float* __restrict__ dinv,
                                                 const float* __restrict__ bias,
                                                 const float* __restrict__ xres,
                                                 float* __restrict__ out, int N) {
    GATHER_BODY({
        float2 xr = ((const float2*)xres)[(size_t)node * 32 + lane];
        float2 r;
        r.x = fmaf(d, ax, bx + xr.x);
        r.y = fmaf(d, ay, by + xr.y);
        ((float2*)out)[(size_t)node * 32 + lane] = r;
    })
}

// ---------------- launch ----------------

extern "C" void kernel_launch(void* const* d_in, const int* in_sizes, int n_in,
                              void* d_out, int out_size, void* d_ws, size_t ws_size,
                              hipStream_t stream) {
    const float* x = (const float*)d_in[0];
    const int* ei = (const int*)d_in[1];  // int32 per harness
    const float* W1 = (const float*)d_in[2];
    const float* b1 = (const float*)d_in[3];
    const float* W2 = (const float*)d_in[4];
    const float* b2 = (const float*)d_in[5];
    float* out = (float*)d_out;

    const int N = in_sizes[0] / DFEAT;          // 100000
    const int E = in_sizes[1] / 2;              // 1600000
    const int NB = (N + BNODES - 1) / BNODES;   // 782

    const int* src = ei;
    const int* dst = ei + E;

    // workspace (~33 MB), 256B-aligned chunks
    char* w = (char*)d_ws;
    size_t o = 0;
    __hip_bfloat16* A = (__hip_bfloat16*)(w + o); o += (size_t)N * DFEAT * 2;        // 12.8 MB
    float* dinv = (float*)(w + o);                o += ((size_t)N * 4 + 255) & ~255; // 0.4 MB
    int* meta = (int*)(w + o);                    o += ((size_t)N * 4 + 255) & ~255; // 0.4 MB
    int* bcur = (int*)(w + o);                    o += ((size_t)NB * 4 + 255) & ~255;
    unsigned* barr = (unsigned*)(w + o);          o += (size_t)NB * BCAP * 4;        // 9.6 MB
    int* csr = (int*)(w + o);                     // 9.6 MB

    const int gB = (E + EPB - 1) / EPB;   // 196
    const int gG = (N + 7) / 8;

    // ---- build (shared by both layers) ----
    zero_cur_k<<<(NB + 255) / 256, 256, 0, stream>>>(bcur, NB);
    bucketize_k<<<gB, 256, 0, stream>>>(src, dst, bcur, barr, E, NB);
    localsort_k<<<NB, 256, 0, stream>>>(bcur, barr, csr, meta, dinv, N);

    // ---- layer 1 ----
    gemm64_k<<<1024, 256, 0, stream>>>(x, W1, dinv, A, N);  // A = bf16(dinv*(x@W1))
    gat_relu_k<<<gG, 256, 0, stream>>>(meta, csr, (const unsigned*)A, dinv, b1, out, N);

    // ---- layer 2 ---- (x1 lives in d_out, consumed by gemm before overwrite)
    gemm64_k<<<1024, 256, 0, stream>>>(out, W2, dinv, A, N);  // A = bf16(dinv*(x1@W2))
    gat_res_k<<<gG, 256, 0, stream>>>(meta, csr, (const unsigned*)A, dinv, b2, x, out, N);
}

// Round 8
// 158.758 us; speedup vs baseline: 10.0496x; 1.3696x over previous
//
#include <hip/hip_runtime.h>
#include <hip/hip_bf16.h>

#define DFEAT 64
#define BNODES 128            // nodes per bucket
#define BCAP 2560             // edge capacity per bucket: mean 2046, sd ~45 -> +11 sigma
#define EPB 8192              // edges per bucketize block (32/thread)

typedef __attribute__((ext_vector_type(8))) short short8;   // 8 bf16 (4 VGPRs)
typedef __attribute__((ext_vector_type(4))) float f32x4;    // MFMA accumulator

// bf16 helpers (raw u16 bit patterns; round-to-nearest-even)
__device__ __forceinline__ unsigned short f2bf(float f) {
    unsigned u = __float_as_uint(f);
    return (unsigned short)((u + 0x7FFFu + ((u >> 16) & 1u)) >> 16);
}
__device__ __forceinline__ float bflo(unsigned u) { return __uint_as_float(u << 16); }
__device__ __forceinline__ float bfhi(unsigned u) { return __uint_as_float(u & 0xFFFF0000u); }

// ---------------- bucket build ----------------

__global__ __launch_bounds__(256) void zero_cur_k(int* __restrict__ bcur, int n) {
    int i = blockIdx.x * 256 + threadIdx.x;
    if (i < n) bcur[i] = 0;
}

// LDS-staged bucketize: per-block histogram, 1 global atomic per non-empty bin,
// scatter packed (dstLocal<<25|src) into reserved contiguous runs.
__global__ __launch_bounds__(256) void bucketize_k(const int* __restrict__ src,
                                                   const int* __restrict__ dst,
                                                   int* __restrict__ bcur,
                                                   unsigned* __restrict__ barr,
                                                   int E, int NB) {
    __shared__ unsigned pkbuf[EPB];
    __shared__ unsigned short bbuf[EPB];
    __shared__ int hist[784];
    __shared__ int base[784];

    int tid = threadIdx.x;
    int e0 = blockIdx.x * EPB;
    int n = min(EPB, E - e0);

    for (int t = tid; t < NB; t += 256) hist[t] = 0;
    __syncthreads();

    for (int k = 0; k < EPB / 256; ++k) {
        int i = k * 256 + tid;
        if (i < n) {
            int d = dst[e0 + i];
            int b = d >> 7;
            pkbuf[i] = ((unsigned)(d & 127) << 25) | (unsigned)src[e0 + i];
            bbuf[i] = (unsigned short)b;
            atomicAdd(&hist[b], 1);
        }
    }
    __syncthreads();

    for (int t = tid; t < NB; t += 256) {
        int c = hist[t];
        if (c > 0) base[t] = atomicAdd(&bcur[t], c);
        hist[t] = 0;
    }
    __syncthreads();

    for (int k = 0; k < EPB / 256; ++k) {
        int i = k * 256 + tid;
        if (i < n) {
            int b = bbuf[i];
            int loc = atomicAdd(&hist[b], 1);
            int pos = base[b] + loc;
            if (pos < BCAP) barr[(size_t)b * BCAP + pos] = pkbuf[i];
        }
    }
}

// one block per bucket: count, LDS scan, scatter into sorted order, write back
// IN PLACE over barr (all reads precede writes), plus meta (off<<16|cnt) + dinv.
__global__ __launch_bounds__(256) void localsort_k(const int* __restrict__ bcur,
                                                   unsigned* __restrict__ barr,
                                                   int* __restrict__ meta,
                                                   float* __restrict__ dinv, int N) {
    __shared__ int cnt[BNODES];
    __shared__ int off[BNODES];
    __shared__ int cur[BNODES];
    __shared__ int sorted[BCAP];
    int b = blockIdx.x;
    int nb = min(bcur[b], BCAP);
    const unsigned* p = barr + (size_t)b * BCAP;
    if (threadIdx.x < BNODES) cnt[threadIdx.x] = 0;
    __syncthreads();
    for (int i = threadIdx.x; i < nb; i += 256) atomicAdd(&cnt[p[i] >> 25], 1);
    __syncthreads();
    if (threadIdx.x < BNODES) off[threadIdx.x] = cnt[threadIdx.x];
    __syncthreads();
    for (int d = 1; d < BNODES; d <<= 1) {
        int v = 0;
        if (threadIdx.x < BNODES && threadIdx.x >= d) v = off[threadIdx.x - d];
        __syncthreads();
        if (threadIdx.x < BNODES) off[threadIdx.x] += v;
        __syncthreads();
    }
    if (threadIdx.x < BNODES) {
        int ex = off[threadIdx.x] - cnt[threadIdx.x];
        cur[threadIdx.x] = ex;
        int node = b * BNODES + threadIdx.x;
        if (node < N) {
            meta[node] = (ex << 16) | cnt[threadIdx.x];
            dinv[node] = rsqrtf((float)cnt[threadIdx.x] + 1.0f);  // +1 self loop
        }
    }
    __syncthreads();
    for (int i = threadIdx.x; i < nb; i += 256) {
        unsigned w = p[i];
        int pos = atomicAdd(&cur[w >> 25], 1);
        sorted[pos] = (int)(w & 0x1FFFFFFu);
    }
    __syncthreads();
    int tot = off[BNODES - 1];
    for (int i = threadIdx.x; i < tot; i += 256)
        barr[(size_t)b * BCAP + i] = (unsigned)sorted[i];
}

// ---------------- W fragment prep + x->bf16 convert ----------------

// Wf flat layout: ((kb*4+ct)*64 + lane)*8 + j  <-  W[kb*32+(lane>>4)*8+j][ct*16+(lane&15)]
__global__ __launch_bounds__(256) void prepW_k(const float* __restrict__ W1,
                                               const float* __restrict__ W2,
                                               unsigned short* __restrict__ W1f,
                                               unsigned short* __restrict__ W2f) {
    for (int idx = threadIdx.x; idx < 4096; idx += 256) {
        int j = idx & 7, lane = (idx >> 3) & 63, ct = (idx >> 9) & 3, kb = (idx >> 11) & 1;
        int k = kb * 32 + (lane >> 4) * 8 + j;
        int col = ct * 16 + (lane & 15);
        W1f[idx] = f2bf(W1[k * 64 + col]);
        W2f[idx] = f2bf(W2[k * 64 + col]);
    }
}

__global__ __launch_bounds__(256) void cvt_k(const float* __restrict__ x,
                                             unsigned short* __restrict__ Xb, int nq) {
    int i = blockIdx.x * 256 + threadIdx.x;
    if (i >= nq) return;
    float4 v = ((const float4*)x)[i];
    ushort4 r;
    r.x = f2bf(v.x); r.y = f2bf(v.y); r.z = f2bf(v.z); r.w = f2bf(v.w);
    ((ushort4*)Xb)[i] = r;
}

// ---------------- MFMA GEMM: Ab[n,64] = bf16( dinv[n] * (Xb[n,64] @ W[64,64]) ) ----------------
// One wave = 16-row x 64-col tile: 8x mfma_f32_16x16x32_bf16.

__global__ __launch_bounds__(256) void mgemm_k(const unsigned short* __restrict__ Xb,
                                               const unsigned short* __restrict__ Wf,
                                               const float* __restrict__ dinv,
                                               unsigned short* __restrict__ Ab,
                                               int ntile, int N) {
    int wv = threadIdx.x >> 6, l = threadIdx.x & 63;
    int tile = blockIdx.x * 4 + wv;
    if (tile >= ntile) return;
    int row0 = tile * 16;

    const short8* Xv = (const short8*)Xb;          // 8-elem (16B) units
    int ar = row0 + (l & 15);
    short8 a0 = Xv[ar * 8 + (l >> 4)];             // k = 0..31
    short8 a1 = Xv[ar * 8 + 4 + (l >> 4)];         // k = 32..63

    const short8* Wv = (const short8*)Wf;          // [(kb*4+ct)*64 + lane]
    int rbase = row0 + (l >> 4) * 4;
    float dv0 = dinv[rbase + 0], dv1 = dinv[rbase + 1];
    float dv2 = dinv[rbase + 2], dv3 = dinv[rbase + 3];

#pragma unroll
    for (int ct = 0; ct < 4; ++ct) {
        f32x4 c = {0.0f, 0.0f, 0.0f, 0.0f};
        c = __builtin_amdgcn_mfma_f32_16x16x32_bf16(a0, Wv[ct * 64 + l], c, 0, 0, 0);
        c = __builtin_amdgcn_mfma_f32_16x16x32_bf16(a1, Wv[(4 + ct) * 64 + l], c, 0, 0, 0);
        int colb = ct * 16 + (l & 15);
        Ab[(size_t)(rbase + 0) * 64 + colb] = f2bf(c[0] * dv0);
        Ab[(size_t)(rbase + 1) * 64 + colb] = f2bf(c[1] * dv1);
        Ab[(size_t)(rbase + 2) * 64 + colb] = f2bf(c[2] * dv2);
        Ab[(size_t)(rbase + 3) * 64 + colb] = f2bf(c[3] * dv3);
    }
}

// ---------------- gather aggregation: 2 nodes per wave, 32 lanes per bf16 row ----------------

#define GATHER_BODY(EPILOGUE)                                                     \
    int lane = threadIdx.x & 31;                                                  \
    int node = blockIdx.x * 8 + (threadIdx.x >> 5);                               \
    if (node >= N) return;                                                        \
    int m = meta[node];                                                           \
    int cnt = m & 0xFFFF;                                                         \
    const int* lst = (const int*)ed + (size_t)(node >> 7) * BCAP + (m >> 16);     \
    unsigned su = Au[(size_t)node * 32 + lane];                                   \
    float ax = bflo(su), ay = bfhi(su); /* self loop */                           \
    int i = 0;                                                                    \
    for (; i + 4 <= cnt; i += 4) {                                                \
        int s0 = lst[i], s1 = lst[i + 1], s2 = lst[i + 2], s3 = lst[i + 3];       \
        unsigned u0 = Au[(size_t)s0 * 32 + lane];                                 \
        unsigned u1 = Au[(size_t)s1 * 32 + lane];                                 \
        unsigned u2 = Au[(size_t)s2 * 32 + lane];                                 \
        unsigned u3 = Au[(size_t)s3 * 32 + lane];                                 \
        ax += (bflo(u0) + bflo(u1)) + (bflo(u2) + bflo(u3));                      \
        ay += (bfhi(u0) + bfhi(u1)) + (bfhi(u2) + bfhi(u3));                      \
    }                                                                             \
    for (; i < cnt; ++i) {                                                        \
        unsigned u = Au[(size_t)lst[i] * 32 + lane];                              \
        ax += bflo(u);                                                            \
        ay += bfhi(u);                                                            \
    }                                                                             \
    float d = dinv[node];                                                         \
    float bx = bias[2 * lane], by = bias[2 * lane + 1];                           \
    EPILOGUE;

// layer-1: writes bf16 x1 (packed u32) -- consumed only by GEMM-2
__global__ __launch_bounds__(256) void gat_relu_k(const int* __restrict__ meta,
                                                  const unsigned* __restrict__ ed,
                                                  const unsigned* __restrict__ Au,
                                                  const float* __restrict__ dinv,
                                                  const float* __restrict__ bias,
                                                  unsigned* __restrict__ xout, int N) {
    GATHER_BODY({
        float rx = fmaxf(fmaf(d, ax, bx), 0.0f);
        float ry = fmaxf(fmaf(d, ay, by), 0.0f);
        xout[(size_t)node * 32 + lane] = ((unsigned)f2bf(ry) << 16) | (unsigned)f2bf(rx);
    })
}

__global__ __launch_bounds__(256) void gat_res_k(const int* __restrict__ meta,
                                                 const unsigned* __restrict__ ed,
                                                 const unsigned* __restrict__ Au,
                                                 const float* __restrict__ dinv,
                                                 const float* __restrict__ bias,
                                                 const float* __restrict__ xres,
                                                 float* __restrict__ out, int N) {
    GATHER_BODY({
        float2 xr = ((const float2*)xres)[(size_t)node * 32 + lane];
        float2 r;
        r.x = fmaf(d, ax, bx + xr.x);
        r.y = fmaf(d, ay, by + xr.y);
        ((float2*)out)[(size_t)node * 32 + lane] = r;
    })
}

// ---------------- launch ----------------

extern "C" void kernel_launch(void* const* d_in, const int* in_sizes, int n_in,
                              void* d_out, int out_size, void* d_ws, size_t ws_size,
                              hipStream_t stream) {
    const float* x = (const float*)d_in[0];
    const int* ei = (const int*)d_in[1];  // int32 per harness
    const float* W1 = (const float*)d_in[2];
    const float* b1 = (const float*)d_in[3];
    const float* W2 = (const float*)d_in[4];
    const float* b2 = (const float*)d_in[5];
    float* out = (float*)d_out;

    const int N = in_sizes[0] / DFEAT;          // 100000
    const int E = in_sizes[1] / 2;              // 1600000
    const int NB = (N + BNODES - 1) / BNODES;   // 782
    const int NT = (N + 15) / 16;               // 6250 row tiles

    const int* src = ei;
    const int* dst = ei + E;

    // workspace (~34.4 MB), 256B-aligned chunks
    char* w = (char*)d_ws;
    size_t o = 0;
    unsigned short* Xb = (unsigned short*)(w + o); o += (size_t)N * DFEAT * 2;        // 12.8 MB
    unsigned short* Ab = (unsigned short*)(w + o); o += (size_t)N * DFEAT * 2;        // 12.8 MB
    float* dinv = (float*)(w + o);                 o += ((size_t)N * 4 + 255) & ~255; // 0.4 MB
    int* meta = (int*)(w + o);                     o += ((size_t)N * 4 + 255) & ~255; // 0.4 MB
    int* bcur = (int*)(w + o);                     o += ((size_t)NB * 4 + 255) & ~255;
    unsigned short* W1f = (unsigned short*)(w + o); o += 4096 * 2;
    unsigned short* W2f = (unsigned short*)(w + o); o += 4096 * 2;
    o = (o + 255) & ~255;
    unsigned* barr = (unsigned*)(w + o);           // NB*BCAP*4 = 8.0 MB (sorted in place)

    const int gB = (E + EPB - 1) / EPB;
    const int gG = (N + 7) / 8;
    const int gM = (NT + 3) / 4;

    // ---- build (shared by both layers) ----
    zero_cur_k<<<(NB + 255) / 256, 256, 0, stream>>>(bcur, NB);
    bucketize_k<<<gB, 256, 0, stream>>>(src, dst, bcur, barr, E, NB);
    localsort_k<<<NB, 256, 0, stream>>>(bcur, barr, meta, dinv, N);
    cvt_k<<<(N * DFEAT / 4 + 255) / 256, 256, 0, stream>>>(x, Xb, N * DFEAT / 4);
    prepW_k<<<1, 256, 0, stream>>>(W1, W2, W1f, W2f);

    // ---- layer 1 ----
    mgemm_k<<<gM, 256, 0, stream>>>(Xb, W1f, dinv, Ab, NT, N);   // Ab = bf16(dinv*(x@W1))
    gat_relu_k<<<gG, 256, 0, stream>>>(meta, barr, (const unsigned*)Ab, dinv, b1,
                                       (unsigned*)Xb, N);        // Xb = bf16(x1)

    // ---- layer 2 ----
    mgemm_k<<<gM, 256, 0, stream>>>(Xb, W2f, dinv, Ab, NT, N);   // Ab = bf16(dinv*(x1@W2))
    gat_res_k<<<gG, 256, 0, stream>>>(meta, barr, (const unsigned*)Ab, dinv, b2, x, out, N);
}

// Round 10
// 149.227 us; speedup vs baseline: 10.6914x; 1.0639x over previous
//
#include <hip/hip_runtime.h>
#include <hip/hip_bf16.h>

#define DFEAT 64
#define BNODES 128            // nodes per bucket
#define BCAP 2560             // edge capacity per bucket: mean 2046, sd ~45 -> +11 sigma
#define EPB 2048              // edges per bucketize block (8/thread)

typedef __attribute__((ext_vector_type(8))) short short8;   // 8 bf16 (4 VGPRs)
typedef __attribute__((ext_vector_type(4))) float f32x4;    // MFMA accumulator

__device__ __forceinline__ unsigned short f2bf(float f) {
    unsigned u = __float_as_uint(f);
    return (unsigned short)((u + 0x7FFFu + ((u >> 16) & 1u)) >> 16);
}
__device__ __forceinline__ float bflo(unsigned u) { return __uint_as_float(u << 16); }
__device__ __forceinline__ float bfhi(unsigned u) { return __uint_as_float(u & 0xFFFF0000u); }

// ---------------- bucket build ----------------

__global__ __launch_bounds__(256) void zero_cur_k(int* __restrict__ bcur, int n) {
    int i = blockIdx.x * 256 + threadIdx.x;
    if (i < n) bcur[i] = 0;
}

// LDS-staged bucketize: per-block histogram, 1 global atomic per non-empty bin,
// scatter packed (dstLocal<<25|src) into reserved contiguous runs.
__global__ __launch_bounds__(256) void bucketize_k(const int* __restrict__ src,
                                                   const int* __restrict__ dst,
                                                   int* __restrict__ bcur,
                                                   unsigned* __restrict__ barr,
                                                   int E, int NB) {
    __shared__ unsigned pkbuf[EPB];
    __shared__ unsigned short bbuf[EPB];
    __shared__ int hist[784];
    __shared__ int base[784];

    int tid = threadIdx.x;
    int e0 = blockIdx.x * EPB;
    int n = min(EPB, E - e0);

    for (int t = tid; t < NB; t += 256) hist[t] = 0;
    __syncthreads();

    for (int k = 0; k < EPB / 256; ++k) {
        int i = k * 256 + tid;
        if (i < n) {
            int d = dst[e0 + i];
            int b = d >> 7;
            pkbuf[i] = ((unsigned)(d & 127) << 25) | (unsigned)src[e0 + i];
            bbuf[i] = (unsigned short)b;
            atomicAdd(&hist[b], 1);
        }
    }
    __syncthreads();

    for (int t = tid; t < NB; t += 256) {
        int c = hist[t];
        if (c > 0) base[t] = atomicAdd(&bcur[t], c);
        hist[t] = 0;
    }
    __syncthreads();

    for (int k = 0; k < EPB / 256; ++k) {
        int i = k * 256 + tid;
        if (i < n) {
            int b = bbuf[i];
            int loc = atomicAdd(&hist[b], 1);
            int pos = base[b] + loc;
            if (pos < BCAP) barr[(size_t)b * BCAP + pos] = pkbuf[i];
        }
    }
}

// one block per bucket: count, LDS scan, scatter sorted, write back IN PLACE,
// plus meta (off<<16|cnt) + dinv.
__global__ __launch_bounds__(256) void localsort_k(const int* __restrict__ bcur,
                                                   unsigned* __restrict__ barr,
                                                   int* __restrict__ meta,
                                                   float* __restrict__ dinv, int N) {
    __shared__ int cnt[BNODES];
    __shared__ int off[BNODES];
    __shared__ int cur[BNODES];
    __shared__ int sorted[BCAP];
    int b = blockIdx.x;
    int nb = min(bcur[b], BCAP);
    const unsigned* p = barr + (size_t)b * BCAP;
    if (threadIdx.x < BNODES) cnt[threadIdx.x] = 0;
    __syncthreads();
    for (int i = threadIdx.x; i < nb; i += 256) atomicAdd(&cnt[p[i] >> 25], 1);
    __syncthreads();
    if (threadIdx.x < BNODES) off[threadIdx.x] = cnt[threadIdx.x];
    __syncthreads();
    for (int d = 1; d < BNODES; d <<= 1) {
        int v = 0;
        if (threadIdx.x < BNODES && threadIdx.x >= d) v = off[threadIdx.x - d];
        __syncthreads();
        if (threadIdx.x < BNODES) off[threadIdx.x] += v;
        __syncthreads();
    }
    if (threadIdx.x < BNODES) {
        int ex = off[threadIdx.x] - cnt[threadIdx.x];
        cur[threadIdx.x] = ex;
        int node = b * BNODES + threadIdx.x;
        if (node < N) {
            meta[node] = (ex << 16) | cnt[threadIdx.x];
            dinv[node] = rsqrtf((float)cnt[threadIdx.x] + 1.0f);  // +1 self loop
        }
    }
    __syncthreads();
    for (int i = threadIdx.x; i < nb; i += 256) {
        unsigned w = p[i];
        int pos = atomicAdd(&cur[w >> 25], 1);
        sorted[pos] = (int)(w & 0x1FFFFFFu);
    }
    __syncthreads();
    int tot = off[BNODES - 1];
    for (int i = threadIdx.x; i < tot; i += 256)
        barr[(size_t)b * BCAP + i] = (unsigned)sorted[i];
}

// ---------------- W fragment prep ----------------

// Wf flat layout: ((kb*4+ct)*64 + lane)*8 + j  <-  W[kb*32+(lane>>4)*8+j][ct*16+(lane&15)]
__global__ __launch_bounds__(256) void prepW_k(const float* __restrict__ W1,
                                               const float* __restrict__ W2,
                                               unsigned short* __restrict__ W1f,
                                               unsigned short* __restrict__ W2f) {
    for (int idx = threadIdx.x; idx < 4096; idx += 256) {
        int j = idx & 7, lane = (idx >> 3) & 63, ct = (idx >> 9) & 3, kb = (idx >> 11) & 1;
        int k = kb * 32 + (lane >> 4) * 8 + j;
        int col = ct * 16 + (lane & 15);
        W1f[idx] = f2bf(W1[k * 64 + col]);
        W2f[idx] = f2bf(W2[k * 64 + col]);
    }
}

// ---------------- MFMA GEMM: Ab[n,64] = bf16( dinv[n] * (X[n,64] @ W[64,64]) ) ----------------
// One wave = 16 rows x 64 cols: 8x mfma_f32_16x16x32_bf16. F32IN: convert x on the fly.

template <bool F32IN>
__global__ __launch_bounds__(256) void mgemm_k(const void* __restrict__ Xin,
                                               const unsigned short* __restrict__ Wf,
                                               const float* __restrict__ dinv,
                                               unsigned short* __restrict__ Ab,
                                               int ntile, int N) {
    int wv = threadIdx.x >> 6, l = threadIdx.x & 63;
    int tile = blockIdx.x * 4 + wv;
    if (tile >= ntile) return;
    int row0 = tile * 16;
    int ar = row0 + (l & 15);

    short8 a0, a1;
    if constexpr (F32IN) {
        const float* Xf = (const float*)Xin;
        const float4* q = (const float4*)(Xf + (size_t)ar * 64 + (l >> 4) * 8);
        float4 f0 = q[0], f1 = q[1];
        const float4* q2 = (const float4*)(Xf + (size_t)ar * 64 + 32 + (l >> 4) * 8);
        float4 g0 = q2[0], g1 = q2[1];
        a0[0]=(short)f2bf(f0.x); a0[1]=(short)f2bf(f0.y); a0[2]=(short)f2bf(f0.z); a0[3]=(short)f2bf(f0.w);
        a0[4]=(short)f2bf(f1.x); a0[5]=(short)f2bf(f1.y); a0[6]=(short)f2bf(f1.z); a0[7]=(short)f2bf(f1.w);
        a1[0]=(short)f2bf(g0.x); a1[1]=(short)f2bf(g0.y); a1[2]=(short)f2bf(g0.z); a1[3]=(short)f2bf(g0.w);
        a1[4]=(short)f2bf(g1.x); a1[5]=(short)f2bf(g1.y); a1[6]=(short)f2bf(g1.z); a1[7]=(short)f2bf(g1.w);
    } else {
        const short8* Xv = (const short8*)Xin;
        a0 = Xv[ar * 8 + (l >> 4)];
        a1 = Xv[ar * 8 + 4 + (l >> 4)];
    }

    const short8* Wv = (const short8*)Wf;
    int rbase = row0 + (l >> 4) * 4;
    float dv0 = dinv[rbase + 0], dv1 = dinv[rbase + 1];
    float dv2 = dinv[rbase + 2], dv3 = dinv[rbase + 3];

#pragma unroll
    for (int ct = 0; ct < 4; ++ct) {
        f32x4 c = {0.0f, 0.0f, 0.0f, 0.0f};
        c = __builtin_amdgcn_mfma_f32_16x16x32_bf16(a0, Wv[ct * 64 + l], c, 0, 0, 0);
        c = __builtin_amdgcn_mfma_f32_16x16x32_bf16(a1, Wv[(4 + ct) * 64 + l], c, 0, 0, 0);
        int colb = ct * 16 + (l & 15);
        Ab[(size_t)(rbase + 0) * 64 + colb] = f2bf(c[0] * dv0);
        Ab[(size_t)(rbase + 1) * 64 + colb] = f2bf(c[1] * dv1);
        Ab[(size_t)(rbase + 2) * 64 + colb] = f2bf(c[2] * dv2);
        Ab[(size_t)(rbase + 3) * 64 + colb] = f2bf(c[3] * dv3);
    }
}

// ---------------- gather aggregation ----------------
// Half-wave (32 lanes) per node: 8 lanes x 16B per row, 4 edges per instruction,
// 8-edge unrolled steady state; shfl_xor(8,16) reduce; epilogue on lanes 0-7.
// NOTE: variadic macro -- braces don't protect commas in macro args, __VA_ARGS__ does.

#define GATHER_BODY(...)                                                            \
    int tid = threadIdx.x;                                                          \
    int lane = tid & 31;                                                            \
    int g = lane >> 3;      /* edge group 0..3 */                                   \
    int sl = lane & 7;      /* 16B slot in row */                                   \
    int node = blockIdx.x * 8 + (tid >> 5);                                         \
    if (node >= N) return;                                                          \
    int m = meta[node];                                                             \
    int cnt = m & 0xFFFF;                                                           \
    const int* lst = (const int*)ed + (size_t)(node >> 7) * BCAP + (m >> 16);       \
    const uint4* A4 = (const uint4*)Au;                                             \
    float a0 = 0, a1 = 0, a2 = 0, a3 = 0, a4 = 0, a5 = 0, a6 = 0, a7 = 0;           \
    if (g == 0) { /* self loop */                                                   \
        uint4 su = A4[(size_t)node * 8 + sl];                                       \
        a0 = bflo(su.x); a1 = bfhi(su.x); a2 = bflo(su.y); a3 = bfhi(su.y);         \
        a4 = bflo(su.z); a5 = bfhi(su.z); a6 = bflo(su.w); a7 = bfhi(su.w);         \
    }                                                                               \
    int i = 0;                                                                      \
    for (; i + 8 <= cnt; i += 8) {                                                  \
        int sA = lst[i + g];                                                        \
        int sB = lst[i + 4 + g];                                                    \
        uint4 uA = A4[(size_t)sA * 8 + sl];                                         \
        uint4 uB = A4[(size_t)sB * 8 + sl];                                         \
        a0 += bflo(uA.x) + bflo(uB.x); a1 += bfhi(uA.x) + bfhi(uB.x);               \
        a2 += bflo(uA.y) + bflo(uB.y); a3 += bfhi(uA.y) + bfhi(uB.y);               \
        a4 += bflo(uA.z) + bflo(uB.z); a5 += bfhi(uA.z) + bfhi(uB.z);               \
        a6 += bflo(uA.w) + bflo(uB.w); a7 += bfhi(uA.w) + bfhi(uB.w);               \
    }                                                                               \
    for (; i < cnt; i += 4) {                                                       \
        int e = min(i + g, cnt - 1);                                                \
        int s = lst[e];                                                             \
        uint4 u = A4[(size_t)s * 8 + sl];                                           \
        if (i + g >= cnt) { u.x = 0; u.y = 0; u.z = 0; u.w = 0; }                   \
        a0 += bflo(u.x); a1 += bfhi(u.x); a2 += bflo(u.y); a3 += bfhi(u.y);         \
        a4 += bflo(u.z); a5 += bfhi(u.z); a6 += bflo(u.w); a7 += bfhi(u.w);         \
    }                                                                               \
    a0 += __shfl_xor(a0, 8);  a1 += __shfl_xor(a1, 8);                              \
    a2 += __shfl_xor(a2, 8);  a3 += __shfl_xor(a3, 8);                              \
    a4 += __shfl_xor(a4, 8);  a5 += __shfl_xor(a5, 8);                              \
    a6 += __shfl_xor(a6, 8);  a7 += __shfl_xor(a7, 8);                              \
    a0 += __shfl_xor(a0, 16); a1 += __shfl_xor(a1, 16);                             \
    a2 += __shfl_xor(a2, 16); a3 += __shfl_xor(a3, 16);                             \
    a4 += __shfl_xor(a4, 16); a5 += __shfl_xor(a5, 16);                             \
    a6 += __shfl_xor(a6, 16); a7 += __shfl_xor(a7, 16);                             \
    if (g == 0) {                                                                   \
        float d = dinv[node];                                                       \
        float4 b0 = *(const float4*)(bias + sl * 8);                                \
        float4 b1 = *(const float4*)(bias + sl * 8 + 4);                            \
        __VA_ARGS__                                                                 \
    }

// layer-1: writes bf16 x1 (packed) -- consumed only by GEMM-2
__global__ __launch_bounds__(256) void gat_relu_k(const int* __restrict__ meta,
                                                  const unsigned* __restrict__ ed,
                                                  const unsigned short* __restrict__ Au,
                                                  const float* __restrict__ dinv,
                                                  const float* __restrict__ bias,
                                                  unsigned* __restrict__ xout, int N) {
    GATHER_BODY(
        float r0 = fmaxf(fmaf(d, a0, b0.x), 0.0f);
        float r1 = fmaxf(fmaf(d, a1, b0.y), 0.0f);
        float r2 = fmaxf(fmaf(d, a2, b0.z), 0.0f);
        float r3 = fmaxf(fmaf(d, a3, b0.w), 0.0f);
        float r4 = fmaxf(fmaf(d, a4, b1.x), 0.0f);
        float r5 = fmaxf(fmaf(d, a5, b1.y), 0.0f);
        float r6 = fmaxf(fmaf(d, a6, b1.z), 0.0f);
        float r7 = fmaxf(fmaf(d, a7, b1.w), 0.0f);
        uint4 pk;
        pk.x = ((unsigned)f2bf(r1) << 16) | f2bf(r0);
        pk.y = ((unsigned)f2bf(r3) << 16) | f2bf(r2);
        pk.z = ((unsigned)f2bf(r5) << 16) | f2bf(r4);
        pk.w = ((unsigned)f2bf(r7) << 16) | f2bf(r6);
        ((uint4*)xout)[(size_t)node * 8 + sl] = pk;
    )
}

__global__ __launch_bounds__(256) void gat_res_k(const int* __restrict__ meta,
                                                 const unsigned* __restrict__ ed,
                                                 const unsigned short* __restrict__ Au,
                                                 const float* __restrict__ dinv,
                                                 const float* __restrict__ bias,
                                                 const float* __restrict__ xres,
                                                 float* __restrict__ out, int N) {
    GATHER_BODY(
        const float4* xq = (const float4*)(xres + (size_t)node * 64 + sl * 8);
        float4 x0 = xq[0];
        float4 x1 = xq[1];
        float4 r0;
        float4 r1;
        r0.x = fmaf(d, a0, b0.x + x0.x); r0.y = fmaf(d, a1, b0.y + x0.y);
        r0.z = fmaf(d, a2, b0.z + x0.z); r0.w = fmaf(d, a3, b0.w + x0.w);
        r1.x = fmaf(d, a4, b1.x + x1.x); r1.y = fmaf(d, a5, b1.y + x1.y);
        r1.z = fmaf(d, a6, b1.z + x1.z); r1.w = fmaf(d, a7, b1.w + x1.w);
        float4* oq = (float4*)(out + (size_t)node * 64 + sl * 8);
        oq[0] = r0; oq[1] = r1;
    )
}

// ---------------- launch ----------------

extern "C" void kernel_launch(void* const* d_in, const int* in_sizes, int n_in,
                              void* d_out, int out_size, void* d_ws, size_t ws_size,
                              hipStream_t stream) {
    const float* x = (const float*)d_in[0];
    const int* ei = (const int*)d_in[1];  // int32 per harness
    const float* W1 = (const float*)d_in[2];
    const float* b1 = (const float*)d_in[3];
    const float* W2 = (const float*)d_in[4];
    const float* b2 = (const float*)d_in[5];
    float* out = (float*)d_out;

    const int N = in_sizes[0] / DFEAT;          // 100000
    const int E = in_sizes[1] / 2;              // 1600000
    const int NB = (N + BNODES - 1) / BNODES;   // 782
    const int NT = (N + 15) / 16;               // 6250 row tiles

    const int* src = ei;
    const int* dst = ei + E;

    // workspace (~34.4 MB), 256B-aligned chunks
    char* w = (char*)d_ws;
    size_t o = 0;
    unsigned short* Xb = (unsigned short*)(w + o); o += (size_t)N * DFEAT * 2;        // 12.8 MB
    unsigned short* Ab = (unsigned short*)(w + o); o += (size_t)N * DFEAT * 2;        // 12.8 MB
    float* dinv = (float*)(w + o);                 o += ((size_t)N * 4 + 255) & ~255;
    int* meta = (int*)(w + o);                     o += ((size_t)N * 4 + 255) & ~255;
    int* bcur = (int*)(w + o);                     o += ((size_t)NB * 4 + 255) & ~255;
    unsigned short* W1f = (unsigned short*)(w + o); o += 4096 * 2;
    unsigned short* W2f = (unsigned short*)(w + o); o += 4096 * 2;
    o = (o + 255) & ~255;
    unsigned* barr = (unsigned*)(w + o);           // NB*BCAP*4 = 8.0 MB (sorted in place)

    const int gB = (E + EPB - 1) / EPB;   // 782
    const int gG = (N + 7) / 8;
    const int gM = (NT + 3) / 4;

    // ---- build (shared by both layers) ----
    zero_cur_k<<<(NB + 255) / 256, 256, 0, stream>>>(bcur, NB);
    bucketize_k<<<gB, 256, 0, stream>>>(src, dst, bcur, barr, E, NB);
    localsort_k<<<NB, 256, 0, stream>>>(bcur, barr, meta, dinv, N);
    prepW_k<<<1, 256, 0, stream>>>(W1, W2, W1f, W2f);

    // ---- layer 1 ---- (x converted to bf16 inside mgemm)
    mgemm_k<true><<<gM, 256, 0, stream>>>(x, W1f, dinv, Ab, NT, N);
    gat_relu_k<<<gG, 256, 0, stream>>>(meta, barr, Ab, dinv, b1, (unsigned*)Xb, N);

    // ---- layer 2 ----
    mgemm_k<false><<<gM, 256, 0, stream>>>(Xb, W2f, dinv, Ab, NT, N);
    gat_res_k<<<gG, 256, 0, stream>>>(meta, barr, Ab, dinv, b2, x, out, N);
}